// Round 5
// baseline (80.179 us; speedup 1.0000x reference)
//
#include <hip/hip_runtime.h>

#define NB 8
#define NN 2048
#define FIN 256
#define FOUT 128

typedef __attribute__((ext_vector_type(8))) short short8;
typedef __attribute__((ext_vector_type(4))) float f32x4;

static __device__ __forceinline__ unsigned short f2bf(float f) {
    unsigned int u = __float_as_uint(f);
    u += 0x7fffu + ((u >> 16) & 1u);
    return (unsigned short)(u >> 16);
}

// Raw barrier: LDS writes visible (lgkmcnt(0)); global loads stay in flight.
#define BAR_LGKM()                                            \
    do {                                                      \
        asm volatile("s_waitcnt lgkmcnt(0)" ::: "memory");    \
        __builtin_amdgcn_sched_barrier(0);                    \
        __builtin_amdgcn_s_barrier();                         \
        __builtin_amdgcn_sched_barrier(0);                    \
    } while (0)

// K0: adj (134 MB of int 0/1) -> bitmask (4 MB). Pure streaming, no LDS, 32 waves/CU.
// Word (row, jc) bit j = adj[row][jc*64 + j]. Lane l loads adj[base + c*64 + l] so
// __ballot(a_c>0) IS word (seg*4 + c) verbatim.
__global__ __launch_bounds__(256) void adj2bit(
    const int* __restrict__ adj, unsigned long long* __restrict__ bm)
{
    const int t = threadIdx.x;
    const int lane = t & 63;
    const int wid = blockIdx.x * 4 + (t >> 6);   // 8192 waves
    #pragma unroll 1
    for (int s = wid; s < 131072; s += 8192) {   // 131072 segments of 256 j
        const size_t base = (size_t)(s >> 3) * NN + (size_t)(s & 7) * 256;
        int a0 = adj[base + 0 * 64 + lane];
        int a1 = adj[base + 1 * 64 + lane];
        int a2 = adj[base + 2 * 64 + lane];
        int a3 = adj[base + 3 * 64 + lane];
        unsigned long long b0 = __ballot(a0 > 0);
        unsigned long long b1 = __ballot(a1 > 0);
        unsigned long long b2 = __ballot(a2 > 0);
        unsigned long long b3 = __ballot(a3 > 0);
        unsigned long long v = b0;
        v = (lane == 1) ? b1 : v;
        v = (lane == 2) ? b2 : v;
        v = (lane == 3) ? b3 : v;
        if (lane < 4) bm[(size_t)(s >> 3) * 32 + (s & 7) * 4 + lane] = v;
    }
}

// K1: unchanged (verified). Wh = h@W fp32; emits s1/s2 + WhPV bf16 fragments.
// WhPV layout per 64-j chunk: [kt(2)][nt(8)][lane(64)][i(8)],
//   element = Wh[j0 + 32*kt + 8*(lane>>4) + i][16*nt + (lane&15)]
__global__ __launch_bounds__(256) void gat_prep(
    const float* __restrict__ h, const float* __restrict__ W, const float* __restrict__ a,
    unsigned short* __restrict__ whpv, float* __restrict__ s1g, float* __restrict__ s2g)
{
    __shared__ __align__(16) float hT[64 * FIN];
    __shared__ __align__(16) unsigned short pvs[8192];
    const int t = threadIdx.x;
    const int bx = blockIdx.x;
    const int b = bx >> 5;
    const int jt = bx & 31;
    const int j0 = jt * 64;

    const float* hsrc = h + ((size_t)b * NN + j0) * FIN;
    #pragma unroll
    for (int p = 0; p < 16; ++p) {
        int idx = p * 256 + t;
        *(f32x4*)&hT[idx * 4] = *(const f32x4*)&hsrc[idx * 4];
    }
    __syncthreads();

    const int cg = t & 31;
    const int rg = t >> 5;
    float acc[8][4];
    #pragma unroll
    for (int r = 0; r < 8; ++r)
        #pragma unroll
        for (int q = 0; q < 4; ++q) acc[r][q] = 0.f;

    for (int f = 0; f < FIN; f += 4) {
        f32x4 wv[4];
        #pragma unroll
        for (int q = 0; q < 4; ++q) wv[q] = *(const f32x4*)&W[(f + q) * FOUT + cg * 4];
        #pragma unroll
        for (int r = 0; r < 8; ++r) {
            f32x4 hv = *(const f32x4*)&hT[(rg * 8 + r) * FIN + f];
            #pragma unroll
            for (int q = 0; q < 4; ++q) {
                acc[r][0] += hv[q] * wv[q][0];
                acc[r][1] += hv[q] * wv[q][1];
                acc[r][2] += hv[q] * wv[q][2];
                acc[r][3] += hv[q] * wv[q][3];
            }
        }
    }

    f32x4 a1v = *(const f32x4*)&a[cg * 4];
    f32x4 a2v = *(const f32x4*)&a[FOUT + cg * 4];
    #pragma unroll
    for (int r = 0; r < 8; ++r) {
        float p1 = acc[r][0]*a1v[0] + acc[r][1]*a1v[1] + acc[r][2]*a1v[2] + acc[r][3]*a1v[3];
        float p2 = acc[r][0]*a2v[0] + acc[r][1]*a2v[1] + acc[r][2]*a2v[2] + acc[r][3]*a2v[3];
        #pragma unroll
        for (int m = 16; m >= 1; m >>= 1) {
            p1 += __shfl_xor(p1, m, 64);
            p2 += __shfl_xor(p2, m, 64);
        }
        if (cg == 0) {
            s1g[b * NN + j0 + rg * 8 + r] = p1;
            s2g[b * NN + j0 + rg * 8 + r] = p2;
        }
    }

    #pragma unroll
    for (int r = 0; r < 8; ++r) {
        int jl = rg * 8 + r;
        int kt = jl >> 5, j5 = jl & 31, g = j5 >> 3, i = j5 & 7;
        #pragma unroll
        for (int q = 0; q < 4; ++q) {
            int c = cg * 4 + q;
            int lane = g * 16 + (c & 15);
            int nt = c >> 4;
            pvs[((kt * 8 + nt) * 64 + lane) * 8 + i] = f2bf(acc[r][q]);
        }
    }
    __syncthreads();
    unsigned short* dst = whpv + (size_t)(b * 32 + jt) * 8192;
    #pragma unroll
    for (int p = 0; p < 4; ++p) {
        int idx = p * 2048 + t * 8;
        *(short8*)&dst[idx] = *(const short8*)&pvs[idx];
    }
}

// K2 v5: adj -> bitmask reads (4 MB, cache-resident); B fragments direct from L2
// (wave = nt, zero redundancy, no BL staging); LDS = Plds dbuf only (8.4 KB).
__global__ __launch_bounds__(512, 4) void gat_main(
    const unsigned int* __restrict__ bm32, const unsigned short* __restrict__ whpv,
    const float* __restrict__ s1g, const float* __restrict__ s2g, float* __restrict__ out)
{
    __shared__ __align__(16) char Plds[2][32 * 128];   // dbuf: [row][slot^ (16B)]
    __shared__ float Sden[32];

    const int t = threadIdx.x;
    const int bx = blockIdx.x;
    const int b = bx & 7;            // XCD affinity: whpv[b] L2-resident
    const int i0 = (bx >> 3) * 32;

    // P-compute mapping: one row x 4 j's per thread
    const int r  = t >> 4;
    const int jq = t & 15;

    // MFMA mapping: wave w <-> N-tile nt = w; lane covers both M-tiles
    const int lane = t & 63;
    const int w = t >> 6;
    const int g = lane >> 4;
    const int c15 = lane & 15;

    const float s1v = s1g[b * NN + i0 + r];

    f32x4 acc0 = (f32x4){0.f, 0.f, 0.f, 0.f};   // mt=0 (rows 0..15)
    f32x4 acc1 = (f32x4){0.f, 0.f, 0.f, 0.f};   // mt=1 (rows 16..31)
    float ssum = 0.f;

    const unsigned short* whb = whpv + (size_t)b * 32 * 8192;
    const float* s2b = s2g + b * NN;
    // u32 view of bitmask: index (row*32 + jc)*2 + (jq>>3)
    const unsigned int* bmr = bm32 + ((size_t)b * NN + i0 + r) * 64 + (jq >> 3);
    const int jqs = (jq & 7) * 4;

    // this wave's B-fragment base (kt = 0 / 1), chunk stride 8192 shorts
    const unsigned short* wb0 = whb + ((size_t)(0 * 8 + w) * 64 + lane) * 8;
    const unsigned short* wb1 = whb + ((size_t)(1 * 8 + w) * 64 + lane) * 8;

    // depth-2 prefetch
    unsigned int bmv[2];
    short8 bp0[2], bp1[2];
    f32x4 s2r[2];
    bmv[0] = bmr[0];
    bmv[1] = bmr[2];
    bp0[0] = *(const short8*)wb0;
    bp1[0] = *(const short8*)wb1;
    bp0[1] = *(const short8*)(wb0 + 8192);
    bp1[1] = *(const short8*)(wb1 + 8192);
    s2r[0] = *(const f32x4*)&s2b[jq * 4];
    s2r[1] = *(const f32x4*)&s2b[64 + jq * 4];

    const int pbyte = r * 128 + ((jq >> 1) ^ (r & 7)) * 16 + (jq & 1) * 8;
    const int arow0 = c15;         // mt=0
    const int arow1 = 16 + c15;    // mt=1; (arow1 & 7) == (arow0 & 7)

    #pragma unroll 2
    for (int jc = 0; jc < 32; ++jc) {
        const int slot = jc & 1;

        unsigned int bw = bmv[slot];
        short8 f0 = bp0[slot];
        short8 f1 = bp1[slot];
        f32x4 s2v = s2r[slot];

        const int jn = (jc + 2) & 31;
        bmv[slot] = bmr[jn * 2];
        bp0[slot] = *(const short8*)(wb0 + (size_t)jn * 8192);
        bp1[slot] = *(const short8*)(wb1 + (size_t)jn * 8192);
        s2r[slot] = *(const f32x4*)&s2b[jn * 64 + jq * 4];

        const unsigned int nib = bw >> jqs;
        float e0 = s1v + s2v[0]; e0 = fmaxf(e0, 0.2f * e0);
        float p0 = (nib & 1u) ? __expf(e0) : 0.f;
        float e1 = s1v + s2v[1]; e1 = fmaxf(e1, 0.2f * e1);
        float p1 = (nib & 2u) ? __expf(e1) : 0.f;
        float e2 = s1v + s2v[2]; e2 = fmaxf(e2, 0.2f * e2);
        float p2 = (nib & 4u) ? __expf(e2) : 0.f;
        float e3 = s1v + s2v[3]; e3 = fmaxf(e3, 0.2f * e3);
        float p3 = (nib & 8u) ? __expf(e3) : 0.f;
        ssum += (p0 + p1) + (p2 + p3);
        unsigned int pk0 = (unsigned int)f2bf(p0) | ((unsigned int)f2bf(p1) << 16);
        unsigned int pk1 = (unsigned int)f2bf(p2) | ((unsigned int)f2bf(p3) << 16);
        uint2 pk = {pk0, pk1};
        *(uint2*)&Plds[slot][pbyte] = pk;

        BAR_LGKM();   // Plds visible; B/bm/s2 prefetch stays in flight

        #pragma unroll
        for (int kt = 0; kt < 2; ++kt) {
            const int sl = (4 * kt + g) ^ (arow0 & 7);
            short8 af0 = *(const short8*)&Plds[slot][arow0 * 128 + sl * 16];
            short8 af1 = *(const short8*)&Plds[slot][arow1 * 128 + sl * 16];
            short8 bfr = kt ? f1 : f0;
            acc0 = __builtin_amdgcn_mfma_f32_16x16x32_bf16(af0, bfr, acc0, 0, 0, 0);
            acc1 = __builtin_amdgcn_mfma_f32_16x16x32_bf16(af1, bfr, acc1, 0, 0, 0);
        }
    }

    // softmax denominators: reduce over the 16 lanes sharing a row
    {
        float v = ssum;
        #pragma unroll
        for (int m = 8; m >= 1; m >>= 1) v += __shfl_xor(v, m, 64);
        if (jq == 0) Sden[r] = v;
    }
    __syncthreads();

    // epilogue: col = w*16 + (lane&15); rows mt*16 + g*4 + q
    float* ob = out + ((size_t)b * NN + i0) * FOUT;
    const int col = w * 16 + c15;
    #pragma unroll
    for (int q = 0; q < 4; ++q) {
        int row0 = g * 4 + q;
        int row1 = 16 + g * 4 + q;
        ob[(size_t)row0 * FOUT + col] = acc0[q] / Sden[row0];
        ob[(size_t)row1 * FOUT + col] = acc1[q] / Sden[row1];
    }
}

extern "C" void kernel_launch(void* const* d_in, const int* in_sizes, int n_in,
                              void* d_out, int out_size, void* d_ws, size_t ws_size,
                              hipStream_t stream) {
    (void)in_sizes; (void)n_in; (void)out_size; (void)ws_size;
    const float* h   = (const float*)d_in[0];
    const int*   adj = (const int*)d_in[1];
    const float* W   = (const float*)d_in[2];
    const float* a   = (const float*)d_in[3];
    float* out = (float*)d_out;

    unsigned short* whpv = (unsigned short*)d_ws;                               // 4 MB
    float* s1g = (float*)((char*)d_ws + (4u << 20));                            // 64 KB
    float* s2g = (float*)((char*)d_ws + (4u << 20) + (64u << 10));              // 64 KB
    unsigned long long* bm = (unsigned long long*)((char*)d_ws + (8u << 20));   // 4 MB

    adj2bit<<<dim3(2048), dim3(256), 0, stream>>>(adj, bm);
    gat_prep<<<dim3(256), dim3(256), 0, stream>>>(h, W, a, whpv, s1g, s2g);
    gat_main<<<dim3(512), dim3(512), 0, stream>>>((const unsigned int*)bm, whpv, s1g, s2g, out);
}

// Round 7
// 68.631 us; speedup vs baseline: 1.1683x; 1.1683x over previous
//
#include <hip/hip_runtime.h>

#define NB 8
#define NN 2048
#define FIN 256
#define FOUT 128

typedef __attribute__((ext_vector_type(8))) short short8;
typedef __attribute__((ext_vector_type(4))) float f32x4;
typedef __attribute__((ext_vector_type(4))) int i32x4;

static __device__ __forceinline__ unsigned short f2bf(float f) {
    unsigned int u = __float_as_uint(f);
    u += 0x7fffu + ((u >> 16) & 1u);
    return (unsigned short)(u >> 16);
}

// Raw barrier: LDS writes visible (lgkmcnt(0)); global loads stay in flight.
#define BAR_LGKM()                                            \
    do {                                                      \
        asm volatile("s_waitcnt lgkmcnt(0)" ::: "memory");    \
        __builtin_amdgcn_sched_barrier(0);                    \
        __builtin_amdgcn_s_barrier();                         \
        __builtin_amdgcn_sched_barrier(0);                    \
    } while (0)

// K1: unchanged (verified since R1). Wh = h@W fp32; emits s1/s2 + WhPV bf16 fragments.
// WhPV layout per 64-j chunk: [kt(2)][nt(8)][lane(64)][i(8)],
//   element = Wh[j0 + 32*kt + 8*(lane>>4) + i][16*nt + (lane&15)]
__global__ __launch_bounds__(256) void gat_prep(
    const float* __restrict__ h, const float* __restrict__ W, const float* __restrict__ a,
    unsigned short* __restrict__ whpv, float* __restrict__ s1g, float* __restrict__ s2g)
{
    __shared__ __align__(16) float hT[64 * FIN];
    __shared__ __align__(16) unsigned short pvs[8192];
    const int t = threadIdx.x;
    const int bx = blockIdx.x;
    const int b = bx >> 5;
    const int jt = bx & 31;
    const int j0 = jt * 64;

    const float* hsrc = h + ((size_t)b * NN + j0) * FIN;
    #pragma unroll
    for (int p = 0; p < 16; ++p) {
        int idx = p * 256 + t;
        *(f32x4*)&hT[idx * 4] = *(const f32x4*)&hsrc[idx * 4];
    }
    __syncthreads();

    const int cg = t & 31;
    const int rg = t >> 5;
    float acc[8][4];
    #pragma unroll
    for (int r = 0; r < 8; ++r)
        #pragma unroll
        for (int q = 0; q < 4; ++q) acc[r][q] = 0.f;

    for (int f = 0; f < FIN; f += 4) {
        f32x4 wv[4];
        #pragma unroll
        for (int q = 0; q < 4; ++q) wv[q] = *(const f32x4*)&W[(f + q) * FOUT + cg * 4];
        #pragma unroll
        for (int r = 0; r < 8; ++r) {
            f32x4 hv = *(const f32x4*)&hT[(rg * 8 + r) * FIN + f];
            #pragma unroll
            for (int q = 0; q < 4; ++q) {
                acc[r][0] += hv[q] * wv[q][0];
                acc[r][1] += hv[q] * wv[q][1];
                acc[r][2] += hv[q] * wv[q][2];
                acc[r][3] += hv[q] * wv[q][3];
            }
        }
    }

    f32x4 a1v = *(const f32x4*)&a[cg * 4];
    f32x4 a2v = *(const f32x4*)&a[FOUT + cg * 4];
    #pragma unroll
    for (int r = 0; r < 8; ++r) {
        float p1 = acc[r][0]*a1v[0] + acc[r][1]*a1v[1] + acc[r][2]*a1v[2] + acc[r][3]*a1v[3];
        float p2 = acc[r][0]*a2v[0] + acc[r][1]*a2v[1] + acc[r][2]*a2v[2] + acc[r][3]*a2v[3];
        #pragma unroll
        for (int m = 16; m >= 1; m >>= 1) {
            p1 += __shfl_xor(p1, m, 64);
            p2 += __shfl_xor(p2, m, 64);
        }
        if (cg == 0) {
            s1g[b * NN + j0 + rg * 8 + r] = p1;
            s2g[b * NN + j0 + rg * 8 + r] = p2;
        }
    }

    #pragma unroll
    for (int r = 0; r < 8; ++r) {
        int jl = rg * 8 + r;
        int kt = jl >> 5, j5 = jl & 31, g = j5 >> 3, i = j5 & 7;
        #pragma unroll
        for (int q = 0; q < 4; ++q) {
            int c = cg * 4 + q;
            int lane = g * 16 + (c & 15);
            int nt = c >> 4;
            pvs[((kt * 8 + nt) * 64 + lane) * 8 + i] = f2bf(acc[r][q]);
        }
    }
    __syncthreads();
    unsigned short* dst = whpv + (size_t)(b * 32 + jt) * 8192;
    #pragma unroll
    for (int p = 0; p < 4; ++p) {
        int idx = p * 2048 + t * 8;
        *(short8*)&dst[idx] = *(const short8*)&pvs[idx];
    }
}

// K2 v6: M=64 rows/block, 1024 threads (16 waves), grid 256 = 1 block/CU.
// whpv traffic per row halved vs v5; adj read directly with nontemporal loads
// (no L2 pollution of the XCD-resident whpv[b]); s2 staged in LDS once;
// P + B double-buffered in LDS; lgkm-only barrier (prefetch never drained).
__global__ __launch_bounds__(1024, 4) void gat_main(
    const int* __restrict__ adj, const unsigned short* __restrict__ whpv,
    const float* __restrict__ s1g, const float* __restrict__ s2g, float* __restrict__ out)
{
    __shared__ __align__(16) char Plds[2][64 * 128];        // 2 x 8 KB P tiles (swizzled)
    __shared__ __align__(16) unsigned short Bl[2][8192];    // 2 x 16 KB B fragments
    __shared__ __align__(16) float s2s[NN];                 // 8 KB: s2 for whole row
    __shared__ float Sden[64];

    const int t = threadIdx.x;
    const int bx = blockIdx.x;
    const int b = bx & 7;            // XCD affinity: whpv[b] (4 MB) L2-resident
    const int i0 = (bx >> 3) * 64;

    // P path: row r (0..63), j-quad jq (0..15)
    const int r  = t >> 4;
    const int jq = t & 15;

    // MFMA path: wave w (0..15): mg = w>>3 (32-row group), ng = w&7 (16-col group)
    const int lane = t & 63;
    const int w = t >> 6;
    const int mg = w >> 3;
    const int ng = w & 7;
    const int g = lane >> 4;
    const int c15 = lane & 15;

    const float* s2b = s2g + b * NN;
    const float s1v = s1g[b * NN + i0 + r];

    const int* aptr = adj + (size_t)b * NN * NN + (size_t)(i0 + r) * NN + jq * 4;
    const unsigned short* whb = whpv + (size_t)b * 32 * 8192;

    // stage s2 row into LDS (issued first so later prefetch stays outstanding)
    float2 s2tmp = *(const float2*)&s2b[t * 2];

    // depth-2 prefetch (slot-indexed arrays touched only with literal indices)
    i32x4  adjv[2];
    short8 whp[2];
    adjv[0] = __builtin_nontemporal_load((const i32x4*)(aptr));
    whp[0]  = *(const short8*)&whb[t * 8];
    adjv[1] = __builtin_nontemporal_load((const i32x4*)(aptr + 64));
    whp[1]  = *(const short8*)&whb[8192 + t * 8];

    *(float2*)&s2s[t * 2] = s2tmp;

    f32x4 acc0 = (f32x4){0.f, 0.f, 0.f, 0.f};   // mt = 0
    f32x4 acc1 = (f32x4){0.f, 0.f, 0.f, 0.f};   // mt = 1
    float ssum = 0.f;

    const int pbyte = r * 128 + ((jq >> 1) ^ (r & 7)) * 16 + (jq & 1) * 8;
    const int arow0 = mg * 32 + c15;        // mt=0
    const int arow1 = mg * 32 + 16 + c15;   // mt=1; (arow1&7)==(arow0&7)
    const int bsh0 = ((0 * 8 + ng) * 64 + lane) * 8;
    const int bsh1 = ((1 * 8 + ng) * 64 + lane) * 8;

    BAR_LGKM();   // s2s visible; global prefetch in flight

#define GAT_BODY(S, JC)                                                         \
    do {                                                                        \
        i32x4  av = adjv[S];                                                    \
        short8 wv = whp[S];                                                     \
        const int jn = ((JC) + 2) & 31;                                         \
        adjv[S] = __builtin_nontemporal_load((const i32x4*)(aptr + jn * 64));   \
        whp[S]  = *(const short8*)&whb[(size_t)jn * 8192 + t * 8];              \
        f32x4 s2v = *(const f32x4*)&s2s[(JC) * 64 + jq * 4];                    \
        float e0 = s1v + s2v[0]; e0 = fmaxf(e0, 0.2f * e0);                     \
        float p0 = (av.x > 0) ? __expf(e0) : 0.f;                               \
        float e1 = s1v + s2v[1]; e1 = fmaxf(e1, 0.2f * e1);                     \
        float p1 = (av.y > 0) ? __expf(e1) : 0.f;                               \
        float e2 = s1v + s2v[2]; e2 = fmaxf(e2, 0.2f * e2);                     \
        float p2 = (av.z > 0) ? __expf(e2) : 0.f;                               \
        float e3 = s1v + s2v[3]; e3 = fmaxf(e3, 0.2f * e3);                     \
        float p3 = (av.w > 0) ? __expf(e3) : 0.f;                               \
        ssum += (p0 + p1) + (p2 + p3);                                          \
        unsigned int pk0 = (unsigned int)f2bf(p0) | ((unsigned int)f2bf(p1) << 16); \
        unsigned int pk1 = (unsigned int)f2bf(p2) | ((unsigned int)f2bf(p3) << 16); \
        uint2 pk = {pk0, pk1};                                                  \
        *(uint2*)&Plds[S][pbyte] = pk;                                          \
        *(short8*)&Bl[S][t * 8] = wv;                                           \
        BAR_LGKM();                                                             \
        {                                                                       \
            short8 bf0 = *(const short8*)&Bl[S][bsh0];                          \
            int sl0 = (0 + g) ^ (arow0 & 7);                                    \
            short8 af00 = *(const short8*)&Plds[S][arow0 * 128 + sl0 * 16];     \
            short8 af01 = *(const short8*)&Plds[S][arow1 * 128 + sl0 * 16];     \
            acc0 = __builtin_amdgcn_mfma_f32_16x16x32_bf16(af00, bf0, acc0, 0, 0, 0); \
            acc1 = __builtin_amdgcn_mfma_f32_16x16x32_bf16(af01, bf0, acc1, 0, 0, 0); \
            short8 bf1 = *(const short8*)&Bl[S][bsh1];                          \
            int sl1 = (4 + g) ^ (arow0 & 7);                                    \
            short8 af10 = *(const short8*)&Plds[S][arow0 * 128 + sl1 * 16];     \
            short8 af11 = *(const short8*)&Plds[S][arow1 * 128 + sl1 * 16];     \
            acc0 = __builtin_amdgcn_mfma_f32_16x16x32_bf16(af10, bf1, acc0, 0, 0, 0); \
            acc1 = __builtin_amdgcn_mfma_f32_16x16x32_bf16(af11, bf1, acc1, 0, 0, 0); \
        }                                                                       \
        BAR_LGKM();                                                             \
    } while (0)

    for (int jc = 0; jc < 32; jc += 2) {
        GAT_BODY(0, jc);
        GAT_BODY(1, jc + 1);
    }
#undef GAT_BODY

    // denominators: 16 threads share row r
    {
        float v = ssum;
        #pragma unroll
        for (int m = 8; m >= 1; m >>= 1) v += __shfl_xor(v, m, 64);
        if (jq == 0) Sden[r] = v;
    }
    __syncthreads();

    // epilogue: col = ng*16 + c15; rows mg*32 + mt*16 + g*4 + q
    float* ob = out + ((size_t)b * NN + i0) * FOUT;
    const int col = ng * 16 + c15;
    #pragma unroll
    for (int q = 0; q < 4; ++q) {
        int row0 = mg * 32 + g * 4 + q;
        int row1 = mg * 32 + 16 + g * 4 + q;
        __builtin_nontemporal_store(acc0[q] / Sden[row0], &ob[(size_t)row0 * FOUT + col]);
        __builtin_nontemporal_store(acc1[q] / Sden[row1], &ob[(size_t)row1 * FOUT + col]);
    }
}

extern "C" void kernel_launch(void* const* d_in, const int* in_sizes, int n_in,
                              void* d_out, int out_size, void* d_ws, size_t ws_size,
                              hipStream_t stream) {
    (void)in_sizes; (void)n_in; (void)out_size; (void)ws_size;
    const float* h   = (const float*)d_in[0];
    const int*   adj = (const int*)d_in[1];
    const float* W   = (const float*)d_in[2];
    const float* a   = (const float*)d_in[3];
    float* out = (float*)d_out;

    unsigned short* whpv = (unsigned short*)d_ws;                               // 4 MB
    float* s1g = (float*)((char*)d_ws + (4u << 20));                            // 64 KB
    float* s2g = (float*)((char*)d_ws + (4u << 20) + (64u << 10));              // 64 KB

    gat_prep<<<dim3(256), dim3(256), 0, stream>>>(h, W, a, whpv, s1g, s2g);
    gat_main<<<dim3(256), dim3(1024), 0, stream>>>(adj, whpv, s1g, s2g, out);
}